// Round 5
// baseline (1492.592 us; speedup 1.0000x reference)
//
#include <hip/hip_runtime.h>
#include <math.h>

// AxialChannelAttention on MI355X, fp32.
// Decomposition:
//   axial = U[b,r,w] + V[b,r,h]  (separable pooling through linear conv1)
//   lrelu(s) = 0.505*s + 0.495*|s|
//   g_avg+g_max = PS[b,c,w] + QS[b,c,h] + 0.495 * sum_r w2[c,r]*m[b,r,h,w]
//   m = |U_a+V_a| + |U_m+V_m|   (single per-pixel matvec for BOTH branches)
// Round-5: k3 restructured so the weight operand truly lives in SGPRs
// (8 c per wave-pass -> 64 w2 dwords per chunk fits the SGPR file) and all
// LDS reads are dense stride-1 with immediate offsets. k1/k2 unchanged.

#define B_  16
#define C_  256
#define CR_ 64
#define H_  128
#define W_  128
#define NEGINF -3.402823466e38f

constexpr size_t SSTRIDE  = (size_t)B_ * C_ * W_;   // 524288 floats per stat array
constexpr size_t USTRIDE  = (size_t)B_ * CR_ * W_;  // 131072 floats per U array
constexpr size_t PQSTRIDE = (size_t)B_ * C_ * W_;   // 524288 floats per PS/QS

// ---------------- Kernel 1: axial pooling (sum+max over H and over W) ---------
__global__ __launch_bounds__(256) void k1_pool(const float* __restrict__ x,
                                               float* __restrict__ S) {
    const int c = blockIdx.x, b = blockIdx.y;
    const int tid = threadIdx.x;
    const int wg = tid & 31;   // col group: cols wg*4..wg*4+3
    const int rg = tid >> 5;   // 0..7: rows rg + 8k
    const float* xp = x + (size_t)(b * C_ + c) * (H_ * W_);

    __shared__ float rs_l[H_], rm_l[H_];
    __shared__ float cps[8][W_], cpm[8][W_];

    float cs0 = 0.f, cs1 = 0.f, cs2 = 0.f, cs3 = 0.f;
    float cm0 = NEGINF, cm1 = NEGINF, cm2 = NEGINF, cm3 = NEGINF;

#pragma unroll 4
    for (int k = 0; k < 16; ++k) {
        const int h = rg + 8 * k;
        const float4 v = *reinterpret_cast<const float4*>(xp + h * W_ + wg * 4);
        cs0 += v.x; cs1 += v.y; cs2 += v.z; cs3 += v.w;
        cm0 = fmaxf(cm0, v.x); cm1 = fmaxf(cm1, v.y);
        cm2 = fmaxf(cm2, v.z); cm3 = fmaxf(cm3, v.w);
        float rs = (v.x + v.y) + (v.z + v.w);
        float rm = fmaxf(fmaxf(v.x, v.y), fmaxf(v.z, v.w));
#pragma unroll
        for (int m = 1; m < 32; m <<= 1) {   // stays within each 32-lane half
            rs += __shfl_xor(rs, m);
            rm = fmaxf(rm, __shfl_xor(rm, m));
        }
        if (wg == 0) { rs_l[h] = rs; rm_l[h] = rm; }
    }
    *reinterpret_cast<float4*>(&cps[rg][wg * 4]) = make_float4(cs0, cs1, cs2, cs3);
    *reinterpret_cast<float4*>(&cpm[rg][wg * 4]) = make_float4(cm0, cm1, cm2, cm3);
    __syncthreads();

    if (tid < 128) {
        float ssum = 0.f, smax = NEGINF;
#pragma unroll
        for (int g = 0; g < 8; ++g) {
            ssum += cps[g][tid];
            smax = fmaxf(smax, cpm[g][tid]);
        }
        const size_t o = (size_t)(b * C_ + c) * W_ + tid;
        S[0 * SSTRIDE + o] = ssum * (1.0f / 128.0f);      // avg_h[b,c,w]
        S[1 * SSTRIDE + o] = smax;                        // max_h[b,c,w]
        S[2 * SSTRIDE + o] = rs_l[tid] * (1.0f / 128.0f); // avg_w[b,c,h]
        S[3 * SSTRIDE + o] = rm_l[tid];                   // max_w[b,c,h]
    }
}

// ---------------- Kernel 2a: U[src][b][r][t] = sum_c w1[r,c] * S[src][b][c][t]
__global__ __launch_bounds__(128) void k2a_u(const float* __restrict__ S,
                                             const float* __restrict__ w1,
                                             float* __restrict__ U) {
    const int t   = threadIdx.x;   // 0..127 (w or h)
    const int rq  = blockIdx.x;    // 0..15 -> 4 r's per block
    const int src = blockIdx.y;    // 0..3
    const int b   = blockIdx.z;
    const float* in = S + ((size_t)(src * B_ + b) * C_) * W_;

    float acc[4];
#pragma unroll
    for (int i = 0; i < 4; ++i) acc[i] = 0.f;

#pragma unroll 8
    for (int c = 0; c < C_; ++c) {
        const float xv = in[c * W_ + t];
#pragma unroll
        for (int i = 0; i < 4; ++i)
            acc[i] = fmaf(w1[(rq * 4 + i) * C_ + c], xv, acc[i]);  // uniform -> s_load
    }
    float* o = U + ((size_t)(src * B_ + b) * CR_ + rq * 4) * W_;
#pragma unroll
    for (int i = 0; i < 4; ++i) o[i * W_ + t] = acc[i];
}

// ---------------- Kernel 2b: PS/QS (linear part of lrelu through conv2) ------
__global__ __launch_bounds__(128) void k2b_pq(const float* __restrict__ U,
                                              const float* __restrict__ w2,
                                              float* __restrict__ PQ) {
    const int t  = threadIdx.x;  // w or h
    const int cq = blockIdx.x;   // 0..31 -> 8 c's per block
    const int pq = blockIdx.y;   // 0 = PS (from U_a,U_m), 1 = QS (from V_a,V_m)
    const int b  = blockIdx.z;
    const float* u0 = U + ((size_t)((pq * 2 + 0) * B_ + b) * CR_) * W_;
    const float* u1 = U + ((size_t)((pq * 2 + 1) * B_ + b) * CR_) * W_;

    float acc[8];
#pragma unroll
    for (int i = 0; i < 8; ++i) acc[i] = 0.f;

#pragma unroll 8
    for (int r = 0; r < CR_; ++r) {
        const float sv = u0[r * W_ + t] + u1[r * W_ + t];
#pragma unroll
        for (int i = 0; i < 8; ++i)
            acc[i] = fmaf(w2[(cq * 8 + i) * CR_ + r], sv, acc[i]);  // uniform -> s_load
    }
    float* o = PQ + ((size_t)(pq * B_ + b) * C_ + cq * 8) * W_;
#pragma unroll
    for (int i = 0; i < 8; ++i) o[i * W_ + t] = 0.505f * acc[i];
}

// ---------------- Kernel 3: fused abs-matvec + sigmoid + scale ---------------
// Block per (b,h), 512 threads (8 waves). sm[r][w] flat (dense stride-1:
// conflict-free writes AND reads; ds offsets r*512+8w fit the 16-bit imm).
// Wave does 4 passes of 8 c's (wave-uniform cbase -> w2 rows via
// s_load_dwordx8; only 64 w2 dwords live per chunk -> fits SGPR file).
// Lane owns w-pair {2*lane, 2*lane+1}. All acc/mv arrays statically indexed.
__global__ __launch_bounds__(512) void k3_gate(const float* __restrict__ x,
                                               const float* __restrict__ U,
                                               const float* __restrict__ PQ,
                                               const float* __restrict__ w2,
                                               float* __restrict__ out) {
    const int h = blockIdx.x, b = blockIdx.y;
    const int tid = threadIdx.x;

    __shared__ float sm[CR_][W_];  // 32 KB

    const float* Ua = U + (size_t)(0 * B_ + b) * CR_ * W_;
    const float* Um = U + (size_t)(1 * B_ + b) * CR_ * W_;
    const float* Va = U + (size_t)(2 * B_ + b) * CR_ * W_;
    const float* Vm = U + (size_t)(3 * B_ + b) * CR_ * W_;

    for (int idx = tid; idx < CR_ * W_; idx += 512) {
        const int r = idx >> 7, w = idx & 127;       // lanes: consecutive w (coalesced)
        const float va = Va[r * W_ + h];             // wave-uniform -> s_load
        const float vm = Vm[r * W_ + h];
        sm[r][w] = fabsf(Ua[r * W_ + w] + va) + fabsf(Um[r * W_ + w] + vm);
    }
    __syncthreads();

    const int lane = tid & 63;
    const int w0 = lane * 2;                                   // w pair {w0, w0+1}
    const int wid = __builtin_amdgcn_readfirstlane(tid >> 6);  // 0..7, SGPR

    const float* PQ0 = PQ + (size_t)b * C_ * W_;               // PS[b][c][w]
    const float* PQ1 = PQ + PQSTRIDE + (size_t)b * C_ * W_;    // QS[b][c][h]

    for (int p = 0; p < 4; ++p) {
        const int cbase = (wid * 4 + p) * 8;       // wave-uniform, 8 c's

        float ax[8], ay[8];
#pragma unroll
        for (int i = 0; i < 8; ++i) { ax[i] = 0.f; ay[i] = 0.f; }

        for (int r8 = 0; r8 < 8; ++r8) {           // rolled; all arrays static-idx
            float2 mv[8];
#pragma unroll
            for (int j = 0; j < 8; ++j)            // ds_read_b64, imm offsets
                mv[j] = *reinterpret_cast<const float2*>(&sm[r8 * 8 + j][w0]);
#pragma unroll
            for (int i = 0; i < 8; ++i) {
                const float* wr = &w2[(size_t)(cbase + i) * CR_ + r8 * 8];  // s_load_dwordx8
                ax[i] = fmaf(wr[0], mv[0].x, ax[i]);
                ay[i] = fmaf(wr[0], mv[0].y, ay[i]);
                ax[i] = fmaf(wr[1], mv[1].x, ax[i]);
                ay[i] = fmaf(wr[1], mv[1].y, ay[i]);
                ax[i] = fmaf(wr[2], mv[2].x, ax[i]);
                ay[i] = fmaf(wr[2], mv[2].y, ay[i]);
                ax[i] = fmaf(wr[3], mv[3].x, ax[i]);
                ay[i] = fmaf(wr[3], mv[3].y, ay[i]);
                ax[i] = fmaf(wr[4], mv[4].x, ax[i]);
                ay[i] = fmaf(wr[4], mv[4].y, ay[i]);
                ax[i] = fmaf(wr[5], mv[5].x, ax[i]);
                ay[i] = fmaf(wr[5], mv[5].y, ay[i]);
                ax[i] = fmaf(wr[6], mv[6].x, ax[i]);
                ay[i] = fmaf(wr[6], mv[6].y, ay[i]);
                ax[i] = fmaf(wr[7], mv[7].x, ax[i]);
                ay[i] = fmaf(wr[7], mv[7].y, ay[i]);
            }
        }

#pragma unroll
        for (int i = 0; i < 8; ++i) {              // FULL unroll: acc stays in regs
            const int c = cbase + i;
            const float q1 = PQ1[(size_t)c * W_ + h];   // uniform -> s_load
            const float2 p0 = *reinterpret_cast<const float2*>(&PQ0[(size_t)c * W_ + w0]);
            const float zx = p0.x + q1 + 0.495f * ax[i];
            const float zy = p0.y + q1 + 0.495f * ay[i];
            const float sgx = __builtin_amdgcn_rcpf(1.0f + __expf(-zx));
            const float sgy = __builtin_amdgcn_rcpf(1.0f + __expf(-zy));
            const size_t xo = ((size_t)(b * C_ + c) * H_ + h) * W_ + w0;
            const float2 xv = *reinterpret_cast<const float2*>(&x[xo]);
            float2 ov;
            ov.x = xv.x * (1.0f + sgx);
            ov.y = xv.y * (1.0f + sgy);
            *reinterpret_cast<float2*>(&out[xo]) = ov;
        }
    }
}

extern "C" void kernel_launch(void* const* d_in, const int* in_sizes, int n_in,
                              void* d_out, int out_size, void* d_ws, size_t ws_size,
                              hipStream_t stream) {
    (void)in_sizes; (void)n_in; (void)out_size; (void)ws_size;
    const float* x  = (const float*)d_in[0];
    const float* w1 = (const float*)d_in[1];
    const float* w2 = (const float*)d_in[2];
    float* out = (float*)d_out;

    float* S  = (float*)d_ws;              // 4 * 524288 floats
    float* U  = S + 4 * SSTRIDE;           // 4 * 131072 floats
    float* PQ = U + 4 * USTRIDE;           // 2 * 524288 floats
    // total workspace: 3,670,016 floats = 14 MB

    k1_pool<<<dim3(C_, B_), 256, 0, stream>>>(x, S);
    k2a_u  <<<dim3(16, 4, B_), 128, 0, stream>>>(S, w1, U);
    k2b_pq <<<dim3(32, 2, B_), 128, 0, stream>>>(U, w2, PQ);
    k3_gate<<<dim3(H_, B_), 512, 0, stream>>>(x, U, PQ, w2, out);
}